// Round 15
// baseline (380.371 us; speedup 1.0000x reference)
//
#include <hip/hip_runtime.h>

#define N_NODES 100000
#define VROWS   200000          // virtual rows: [0,100000)=feat, [100000,200000)=adj
#define BSHIFT  8
#define BROWS   256             // rows per bucket
#define NBUCK   ((VROWS + BROWS - 1) / BROWS)   // 782
#define BINB    256             // blocks for binA/binB (1024 threads each)
#define BINT    1024            // threads per binA/binB block
#define SCAP    5632            // LDS-cached segment elems in sort (45KB; avg 4604, sigma ~68)

static __device__ __forceinline__ unsigned short f2bf(float x) {
    unsigned u = __float_as_uint(x);
    return (unsigned short)((u + 0x7fffu + ((u >> 16) & 1u)) >> 16);
}
static __device__ __forceinline__ float bf_lo(unsigned u) { return __uint_as_float(u << 16); }
static __device__ __forceinline__ float bf_hi(unsigned u) { return __uint_as_float(u & 0xffff0000u); }

// nt load of a packed (col,val) element via long long (builtin rejects HIP vector types)
static __device__ __forceinline__ void nt_colval(const long long* p, int& c, float& v) {
    long long e = __builtin_nontemporal_load(p);
    c = (int)(e & 0x1ffffLL);
    v = __uint_as_float((unsigned)((unsigned long long)e >> 32));
}

// payload: lo = col(17b) | rowlocal(8b)<<17 ; hi = val bits
static __device__ __forceinline__ long long pack_cv(int col, int rl, float v) {
    unsigned lo = (unsigned)col | ((unsigned)rl << 17);
    return (long long)lo | ((long long)(unsigned)__float_as_uint(v) << 32);
}

// 8-channel accumulate of v * row16B (8 bf16) into two float4
static __device__ __forceinline__ void fma8(float4& lo, float4& hi, float v, const uint4& u) {
    lo.x += v * bf_lo(u.x); lo.y += v * bf_hi(u.x);
    lo.z += v * bf_lo(u.y); lo.w += v * bf_hi(u.y);
    hi.x += v * bf_lo(u.z); hi.y += v * bf_hi(u.z);
    hi.z += v * bf_lo(u.w); hi.w += v * bf_hi(u.w);
}

// ---------------- CSR build: atomic-light two-pass multisplit ----------------

// Pass A: per-block LDS histogram over buckets; ONE global atomic per (block,bucket).
// Blocks 0-31 additionally convert W f32[512,128] -> bf16 pairs (fused wconv).
__global__ __launch_bounds__(BINT) void binA_kernel(
        const int* __restrict__ f_rows, const int* __restrict__ a_rows,
        int* __restrict__ cur, int* __restrict__ pbb,
        const float* __restrict__ W, unsigned* __restrict__ Wbf,
        int nnzf, int nedge) {
    const int t = threadIdx.x;
    if (blockIdx.x < 32) {                      // fused W conversion: 32*1024 = 32768 pairs
        int i = blockIdx.x * BINT + t;
        float a = W[2 * i], b = W[2 * i + 1];
        Wbf[i] = (unsigned)f2bf(a) | ((unsigned)f2bf(b) << 16);
    }
    __shared__ int hist[NBUCK];
    for (int b = t; b < NBUCK; b += BINT) hist[b] = 0;
    __syncthreads();
    {
        const int per = (nnzf + BINB - 1) / BINB;
        const int beg = blockIdx.x * per;
        const int end = min(beg + per, nnzf);
        int i = beg + t;
        for (; i + 3 * BINT < end; i += 4 * BINT) {
            int r0 = f_rows[i], r1 = f_rows[i + BINT], r2 = f_rows[i + 2 * BINT], r3 = f_rows[i + 3 * BINT];
            atomicAdd(&hist[r0 >> BSHIFT], 1);
            atomicAdd(&hist[r1 >> BSHIFT], 1);
            atomicAdd(&hist[r2 >> BSHIFT], 1);
            atomicAdd(&hist[r3 >> BSHIFT], 1);
        }
        for (; i < end; i += BINT) atomicAdd(&hist[f_rows[i] >> BSHIFT], 1);
    }
    {
        const int per = (nedge + BINB - 1) / BINB;
        const int beg = blockIdx.x * per;
        const int end = min(beg + per, nedge);
        int i = beg + t;
        for (; i + 3 * BINT < end; i += 4 * BINT) {
            int r0 = a_rows[i] + N_NODES, r1 = a_rows[i + BINT] + N_NODES;
            int r2 = a_rows[i + 2 * BINT] + N_NODES, r3 = a_rows[i + 3 * BINT] + N_NODES;
            atomicAdd(&hist[r0 >> BSHIFT], 1);
            atomicAdd(&hist[r1 >> BSHIFT], 1);
            atomicAdd(&hist[r2 >> BSHIFT], 1);
            atomicAdd(&hist[r3 >> BSHIFT], 1);
        }
        for (; i < end; i += BINT) atomicAdd(&hist[(a_rows[i] + N_NODES) >> BSHIFT], 1);
    }
    __syncthreads();
    for (int b = t; b < NBUCK; b += BINT) {
        int c = hist[b];
        pbb[blockIdx.x * NBUCK + b] = c ? atomicAdd(&cur[b], c) : 0;
    }
}

// Exclusive scan of 782 bucket counts -> bbase; rp[VROWS] = total.
__global__ void bucket_scan_kernel(const int* __restrict__ cur, int* __restrict__ bbase,
                                   int* __restrict__ rp) {
    __shared__ int sh[1024];
    const int t = threadIdx.x;
    int v = (t < NBUCK) ? cur[t] : 0;
    sh[t] = v;
    __syncthreads();
    for (int off = 1; off < 1024; off <<= 1) {
        int u = (t >= off) ? sh[t - off] : 0;
        __syncthreads();
        sh[t] += u;
        __syncthreads();
    }
    if (t < NBUCK) bbase[t] = sh[t] - v;
    if (t == NBUCK - 1) rp[VROWS] = sh[t];
}

// Pass B: replay chunk; place payloads at bbase[b] + pbb[block][b] + ldscursor.
__global__ __launch_bounds__(BINT) void binB_kernel(
        const int* __restrict__ f_rows, const int* __restrict__ f_cols, const float* __restrict__ f_vals,
        const int* __restrict__ a_rows, const int* __restrict__ a_cols, const float* __restrict__ a_vals,
        const int* __restrict__ bbase, const int* __restrict__ pbb,
        long long* __restrict__ staging, int nnzf, int nedge) {
    __shared__ int curs[NBUCK];
    const int t = threadIdx.x;
    for (int b = t; b < NBUCK; b += BINT) curs[b] = bbase[b] + pbb[blockIdx.x * NBUCK + b];
    __syncthreads();
    {
        const int per = (nnzf + BINB - 1) / BINB;
        const int beg = blockIdx.x * per;
        const int end = min(beg + per, nnzf);
        for (int i = beg + t; i < end; i += BINT) {
            const int   r = f_rows[i];
            const int   c = f_cols[i];
            const float v = f_vals[i];
            const int p = atomicAdd(&curs[r >> BSHIFT], 1);
            staging[p] = pack_cv(c, r & (BROWS - 1), v);
        }
    }
    {
        const int per = (nedge + BINB - 1) / BINB;
        const int beg = blockIdx.x * per;
        const int end = min(beg + per, nedge);
        for (int i = beg + t; i < end; i += BINT) {
            const int   r = a_rows[i] + N_NODES;
            const int   c = a_cols[i];
            const float v = a_vals[i];
            const int p = atomicAdd(&curs[r >> BSHIFT], 1);
            staging[p] = pack_cv(c, r & (BROWS - 1), v);
        }
    }
}

// Per-bucket sort: LDS-cache the segment (one global read), count rows, scan,
// write row_ptr, place into colval (nt stores). Global-tail fallback if n>SCAP.
__global__ __launch_bounds__(256) void sort_kernel(
        const int* __restrict__ cur, const int* __restrict__ bbase,
        const long long* __restrict__ staging, long long* __restrict__ colval,
        int* __restrict__ rp) {
    __shared__ long long sseg[SCAP];    // 45KB
    __shared__ int cnt[BROWS];
    __shared__ int offs[BROWS];
    const int b = blockIdx.x;
    const int t = threadIdx.x;
    const int n = cur[b];
    const int base = bbase[b];
    const long long* seg = staging + base;
    const int m = min(n, SCAP);
    for (int j = t; j < m; j += 256) sseg[j] = seg[j];
    cnt[t] = 0;
    __syncthreads();
    for (int j = t; j < m; j += 256) {
        unsigned lo = (unsigned)(sseg[j] & 0xffffffffLL);
        atomicAdd(&cnt[(lo >> 17) & (BROWS - 1)], 1);
    }
    for (int j = SCAP + t; j < n; j += 256) {           // statistical never
        unsigned lo = (unsigned)(seg[j] & 0xffffffffLL);
        atomicAdd(&cnt[(lo >> 17) & (BROWS - 1)], 1);
    }
    __syncthreads();
    int v = cnt[t];
    offs[t] = v;
    __syncthreads();
    for (int o = 1; o < BROWS; o <<= 1) {
        int u = (t >= o) ? offs[t - o] : 0;
        __syncthreads();
        offs[t] += u;
        __syncthreads();
    }
    const int excl = offs[t] - v;
    offs[t] = base + excl;           // absolute placement cursor
    const int row = (b << BSHIFT) + t;
    if (row < VROWS) rp[row] = base + excl;
    __syncthreads();
    for (int j = t; j < m; j += 256) {
        long long e = sseg[j];
        unsigned lo = (unsigned)(e & 0xffffffffLL);
        const int rl = (lo >> 17) & (BROWS - 1);
        const int p = atomicAdd(&offs[rl], 1);
        __builtin_nontemporal_store((long long)(lo & 0x1ffffu) | (e & 0xffffffff00000000LL),
                                    colval + p);
    }
    for (int j = SCAP + t; j < n; j += 256) {           // statistical never
        long long e = seg[j];
        unsigned lo = (unsigned)(e & 0xffffffffLL);
        const int rl = (lo >> 17) & (BROWS - 1);
        const int p = atomicAdd(&offs[rl], 1);
        __builtin_nontemporal_store((long long)(lo & 0x1ffffu) | (e & 0xffffffff00000000LL),
                                    colval + p);
    }
}

// ---------------- gathers: quarter-wave edges ----------------
// 16 lanes per edge, uint4 (16B = 8 bf16 ch) per lane -> 4 edges per gather
// instruction; ~0.5 vmem instr/edge. Each quarter owns one row.

// feat: gather from bf16 W, +bias, relu, bf16 out
__global__ __launch_bounds__(256) void spmm_feat_q_kernel(
        const int* __restrict__ rp, const long long* __restrict__ colval,
        const uint4* __restrict__ Wbf, const float* __restrict__ bias,
        unsigned short* __restrict__ base_bf, int n) {
    const int wave = (blockIdx.x * blockDim.x + threadIdx.x) >> 6;
    const int lane = threadIdx.x & 63;
    const int q = lane >> 4, ql = lane & 15;
    const int r = wave * 4 + q;
    float4 a0l = make_float4(0.f, 0.f, 0.f, 0.f), a0h = a0l, a1l = a0l, a1h = a0l;
    int i = 0, end = 0;
    if (r < n) { i = rp[r]; end = rp[r + 1]; }
    for (; i + 1 < end; i += 2) {
        int c0, c1; float v0, v1;
        nt_colval(colval + i,     c0, v0);
        nt_colval(colval + i + 1, c1, v1);
        const uint4 u0 = Wbf[c0 * 16 + ql];
        const uint4 u1 = Wbf[c1 * 16 + ql];
        fma8(a0l, a0h, v0, u0);
        fma8(a1l, a1h, v1, u1);
    }
    if (i < end) {
        int c; float v;
        nt_colval(colval + i, c, v);
        const uint4 u = Wbf[c * 16 + ql];
        fma8(a0l, a0h, v, u);
    }
    if (r < n) {
        const float4 bl = ((const float4*)bias)[ql * 2];
        const float4 bh = ((const float4*)bias)[ql * 2 + 1];
        float s0 = fmaxf(a0l.x + a1l.x + bl.x, 0.f), s1 = fmaxf(a0l.y + a1l.y + bl.y, 0.f);
        float s2 = fmaxf(a0l.z + a1l.z + bl.z, 0.f), s3 = fmaxf(a0l.w + a1l.w + bl.w, 0.f);
        float s4 = fmaxf(a0h.x + a1h.x + bh.x, 0.f), s5 = fmaxf(a0h.y + a1h.y + bh.y, 0.f);
        float s6 = fmaxf(a0h.z + a1h.z + bh.z, 0.f), s7 = fmaxf(a0h.w + a1h.w + bh.w, 0.f);
        uint4 o;
        o.x = (unsigned)f2bf(s0) | ((unsigned)f2bf(s1) << 16);
        o.y = (unsigned)f2bf(s2) | ((unsigned)f2bf(s3) << 16);
        o.z = (unsigned)f2bf(s4) | ((unsigned)f2bf(s5) << 16);
        o.w = (unsigned)f2bf(s6) | ((unsigned)f2bf(s7) << 16);
        ((uint4*)(base_bf + (size_t)r * 128))[ql] = o;
    }
}

// adj: bf16 src -> bf16 dst
__global__ __launch_bounds__(256) void spmm_adj_q_bf_kernel(
        const int* __restrict__ rp, const long long* __restrict__ colval,
        const uint4* __restrict__ src, unsigned short* __restrict__ dst, int n) {
    const int wave = (blockIdx.x * blockDim.x + threadIdx.x) >> 6;
    const int lane = threadIdx.x & 63;
    const int q = lane >> 4, ql = lane & 15;
    const int r = wave * 4 + q;
    float4 a0l = make_float4(0.f, 0.f, 0.f, 0.f), a0h = a0l, a1l = a0l, a1h = a0l;
    int i = 0, end = 0;
    if (r < n) { i = rp[r]; end = rp[r + 1]; }
    for (; i + 1 < end; i += 2) {
        int c0, c1; float v0, v1;
        nt_colval(colval + i,     c0, v0);
        nt_colval(colval + i + 1, c1, v1);
        const uint4 u0 = src[c0 * 16 + ql];
        const uint4 u1 = src[c1 * 16 + ql];
        fma8(a0l, a0h, v0, u0);
        fma8(a1l, a1h, v1, u1);
    }
    if (i < end) {
        int c; float v;
        nt_colval(colval + i, c, v);
        const uint4 u = src[c * 16 + ql];
        fma8(a0l, a0h, v, u);
    }
    if (r < n) {
        uint4 o;
        o.x = (unsigned)f2bf(a0l.x + a1l.x) | ((unsigned)f2bf(a0l.y + a1l.y) << 16);
        o.y = (unsigned)f2bf(a0l.z + a1l.z) | ((unsigned)f2bf(a0l.w + a1l.w) << 16);
        o.z = (unsigned)f2bf(a0h.x + a1h.x) | ((unsigned)f2bf(a0h.y + a1h.y) << 16);
        o.w = (unsigned)f2bf(a0h.z + a1h.z) | ((unsigned)f2bf(a0h.w + a1h.w) << 16);
        ((uint4*)(dst + (size_t)r * 128))[ql] = o;
    }
}

// adj: bf16 src -> f32 dst
__global__ __launch_bounds__(256) void spmm_adj_q_f32_kernel(
        const int* __restrict__ rp, const long long* __restrict__ colval,
        const uint4* __restrict__ src, float* __restrict__ dst, int n) {
    const int wave = (blockIdx.x * blockDim.x + threadIdx.x) >> 6;
    const int lane = threadIdx.x & 63;
    const int q = lane >> 4, ql = lane & 15;
    const int r = wave * 4 + q;
    float4 a0l = make_float4(0.f, 0.f, 0.f, 0.f), a0h = a0l, a1l = a0l, a1h = a0l;
    int i = 0, end = 0;
    if (r < n) { i = rp[r]; end = rp[r + 1]; }
    for (; i + 1 < end; i += 2) {
        int c0, c1; float v0, v1;
        nt_colval(colval + i,     c0, v0);
        nt_colval(colval + i + 1, c1, v1);
        const uint4 u0 = src[c0 * 16 + ql];
        const uint4 u1 = src[c1 * 16 + ql];
        fma8(a0l, a0h, v0, u0);
        fma8(a1l, a1h, v1, u1);
    }
    if (i < end) {
        int c; float v;
        nt_colval(colval + i, c, v);
        const uint4 u = src[c * 16 + ql];
        fma8(a0l, a0h, v, u);
    }
    if (r < n) {
        float4 lo, hi;
        lo.x = a0l.x + a1l.x; lo.y = a0l.y + a1l.y; lo.z = a0l.z + a1l.z; lo.w = a0l.w + a1l.w;
        hi.x = a0h.x + a1h.x; hi.y = a0h.y + a1h.y; hi.z = a0h.z + a1h.z; hi.w = a0h.w + a1h.w;
        float4* dr = (float4*)(dst + (size_t)r * 128);
        dr[ql * 2]     = lo;
        dr[ql * 2 + 1] = hi;
    }
}

// ---------------- launch ----------------

extern "C" void kernel_launch(void* const* d_in, const int* in_sizes, int n_in,
                              void* d_out, int out_size, void* d_ws, size_t ws_size,
                              hipStream_t stream) {
    const int*   fi   = (const int*)d_in[0];     // feat_indices [2, nnzf]
    const float* fv   = (const float*)d_in[1];   // feat_values  [nnzf]
    const int*   ai   = (const int*)d_in[2];     // adj_indices  [2, nedge]
    const float* av   = (const float*)d_in[3];   // adj_values   [nedge]
    const float* W    = (const float*)d_in[4];   // weight [512,128]
    const float* bias = (const float*)d_in[5];   // bias [1,128]
    float* out = (float*)d_out;

    const int nnzf  = in_sizes[1];
    const int nedge = in_sizes[3];
    const int ntot  = nnzf + nedge;
    const int* f_rows = fi;
    const int* f_cols = fi + nnzf;
    const int* a_rows = ai;
    const int* a_cols = ai + nedge;

    // bump-allocate workspace (256B aligned)
    char* wp = (char*)d_ws;
    auto balloc = [&](size_t bytes) -> char* {
        char* p = wp;
        wp += (bytes + 255) & ~(size_t)255;
        return p;
    };
    // staging (28.8MB) dead after sort; base_bf (25.6MB) overlays it.
    long long* staging = (long long*)balloc(8ull * (size_t)ntot);
    unsigned short* base_bf = (unsigned short*)staging;
    unsigned short* t1 = (unsigned short*)balloc(2ull * N_NODES * 128);
    long long* colval = (long long*)balloc(8ull * (size_t)ntot);
    int* rp     = (int*)balloc(4ull * (VROWS + 1));
    int* cur    = (int*)balloc(4ull * NBUCK);
    int* bbase  = (int*)balloc(4ull * NBUCK);
    int* pbb    = (int*)balloc(4ull * BINB * NBUCK);
    unsigned* Wbf = (unsigned*)balloc(4ull * 512 * 64);   // 128KB bf16 W

    const int nwaves = (N_NODES + 3) / 4;          // 4 rows per wave
    const int RW = (nwaves + 3) / 4;               // 4 waves per 256-thread block

    // ---- CSR build: memset -> histogram(+wconv) -> scan -> place -> sort ----
    hipMemsetAsync(cur, 0, 4ull * NBUCK, stream);
    binA_kernel<<<BINB, BINT, 0, stream>>>(f_rows, a_rows, cur, pbb, W, Wbf, nnzf, nedge);
    bucket_scan_kernel<<<1, 1024, 0, stream>>>(cur, bbase, rp);
    binB_kernel<<<BINB, BINT, 0, stream>>>(f_rows, f_cols, fv, a_rows, a_cols, av,
                                           bbase, pbb, staging, nnzf, nedge);
    sort_kernel<<<NBUCK, 256, 0, stream>>>(cur, bbase, staging, colval, rp);

    // ---- compute: feat -> base_bf(bf16), adj -> t1(bf16), adj -> out(f32) ----
    spmm_feat_q_kernel<<<RW, 256, 0, stream>>>(rp, colval, (const uint4*)Wbf, bias,
                                               base_bf, N_NODES);
    spmm_adj_q_bf_kernel<<<RW, 256, 0, stream>>>(rp + N_NODES, colval,
                                                 (const uint4*)base_bf, t1, N_NODES);
    spmm_adj_q_f32_kernel<<<RW, 256, 0, stream>>>(rp + N_NODES, colval,
                                                  (const uint4*)t1, out, N_NODES);
}

// Round 16
// 293.846 us; speedup vs baseline: 1.2945x; 1.2945x over previous
//
#include <hip/hip_runtime.h>

#define N_NODES 100000
#define VROWS   200000          // virtual rows: [0,100000)=feat, [100000,200000)=adj
#define BSHIFT  8
#define BROWS   256             // rows per bucket
#define NBUCK   ((VROWS + BROWS - 1) / BROWS)   // 782
#define BINB    256             // blocks for binA/binB (1024 threads each)
#define BINT    1024            // threads per binA/binB block

static __device__ __forceinline__ unsigned short f2bf(float x) {
    unsigned u = __float_as_uint(x);
    return (unsigned short)((u + 0x7fffu + ((u >> 16) & 1u)) >> 16);
}
static __device__ __forceinline__ float bf_lo(unsigned u) { return __uint_as_float(u << 16); }
static __device__ __forceinline__ float bf_hi(unsigned u) { return __uint_as_float(u & 0xffff0000u); }

// nt load of a packed (col,val) element via long long (builtin rejects HIP vector types)
static __device__ __forceinline__ void nt_colval(const long long* p, int& c, float& v) {
    long long e = __builtin_nontemporal_load(p);
    c = (int)(e & 0x1ffffLL);
    v = __uint_as_float((unsigned)((unsigned long long)e >> 32));
}

// payload: lo = col(17b) | rowlocal(8b)<<17 ; hi = val bits
static __device__ __forceinline__ long long pack_cv(int col, int rl, float v) {
    unsigned lo = (unsigned)col | ((unsigned)rl << 17);
    return (long long)lo | ((long long)(unsigned)__float_as_uint(v) << 32);
}

// 8-channel accumulate of v * row16B (8 bf16) into two float4
static __device__ __forceinline__ void fma8(float4& lo, float4& hi, float v, const uint4& u) {
    lo.x += v * bf_lo(u.x); lo.y += v * bf_hi(u.x);
    lo.z += v * bf_lo(u.y); lo.w += v * bf_hi(u.y);
    hi.x += v * bf_lo(u.z); hi.y += v * bf_hi(u.z);
    hi.z += v * bf_lo(u.w); hi.w += v * bf_hi(u.w);
}

// ---------------- CSR build: atomic-light two-pass multisplit ----------------

// Pass A: per-block LDS histogram over buckets; ONE global atomic per (block,bucket).
// Blocks 0-31 additionally convert W f32[512,128] -> bf16 pairs (fused wconv).
__global__ __launch_bounds__(BINT) void binA_kernel(
        const int* __restrict__ f_rows, const int* __restrict__ a_rows,
        int* __restrict__ cur, int* __restrict__ pbb,
        const float* __restrict__ W, unsigned* __restrict__ Wbf,
        int nnzf, int nedge) {
    const int t = threadIdx.x;
    if (blockIdx.x < 32) {                      // fused W conversion: 32*1024 = 32768 pairs
        int i = blockIdx.x * BINT + t;
        float a = W[2 * i], b = W[2 * i + 1];
        Wbf[i] = (unsigned)f2bf(a) | ((unsigned)f2bf(b) << 16);
    }
    __shared__ int hist[NBUCK];
    for (int b = t; b < NBUCK; b += BINT) hist[b] = 0;
    __syncthreads();
    {
        const int per = (nnzf + BINB - 1) / BINB;
        const int beg = blockIdx.x * per;
        const int end = min(beg + per, nnzf);
        int i = beg + t;
        for (; i + 3 * BINT < end; i += 4 * BINT) {
            int r0 = f_rows[i], r1 = f_rows[i + BINT], r2 = f_rows[i + 2 * BINT], r3 = f_rows[i + 3 * BINT];
            atomicAdd(&hist[r0 >> BSHIFT], 1);
            atomicAdd(&hist[r1 >> BSHIFT], 1);
            atomicAdd(&hist[r2 >> BSHIFT], 1);
            atomicAdd(&hist[r3 >> BSHIFT], 1);
        }
        for (; i < end; i += BINT) atomicAdd(&hist[f_rows[i] >> BSHIFT], 1);
    }
    {
        const int per = (nedge + BINB - 1) / BINB;
        const int beg = blockIdx.x * per;
        const int end = min(beg + per, nedge);
        int i = beg + t;
        for (; i + 3 * BINT < end; i += 4 * BINT) {
            int r0 = a_rows[i] + N_NODES, r1 = a_rows[i + BINT] + N_NODES;
            int r2 = a_rows[i + 2 * BINT] + N_NODES, r3 = a_rows[i + 3 * BINT] + N_NODES;
            atomicAdd(&hist[r0 >> BSHIFT], 1);
            atomicAdd(&hist[r1 >> BSHIFT], 1);
            atomicAdd(&hist[r2 >> BSHIFT], 1);
            atomicAdd(&hist[r3 >> BSHIFT], 1);
        }
        for (; i < end; i += BINT) atomicAdd(&hist[(a_rows[i] + N_NODES) >> BSHIFT], 1);
    }
    __syncthreads();
    for (int b = t; b < NBUCK; b += BINT) {
        int c = hist[b];
        pbb[blockIdx.x * NBUCK + b] = c ? atomicAdd(&cur[b], c) : 0;
    }
}

// Exclusive scan of 782 bucket counts -> bbase; rp[VROWS] = total.
__global__ void bucket_scan_kernel(const int* __restrict__ cur, int* __restrict__ bbase,
                                   int* __restrict__ rp) {
    __shared__ int sh[1024];
    const int t = threadIdx.x;
    int v = (t < NBUCK) ? cur[t] : 0;
    sh[t] = v;
    __syncthreads();
    for (int off = 1; off < 1024; off <<= 1) {
        int u = (t >= off) ? sh[t - off] : 0;
        __syncthreads();
        sh[t] += u;
        __syncthreads();
    }
    if (t < NBUCK) bbase[t] = sh[t] - v;
    if (t == NBUCK - 1) rp[VROWS] = sh[t];
}

// Pass B: replay chunk; place payloads at bbase[b] + pbb[block][b] + ldscursor.
__global__ __launch_bounds__(BINT) void binB_kernel(
        const int* __restrict__ f_rows, const int* __restrict__ f_cols, const float* __restrict__ f_vals,
        const int* __restrict__ a_rows, const int* __restrict__ a_cols, const float* __restrict__ a_vals,
        const int* __restrict__ bbase, const int* __restrict__ pbb,
        long long* __restrict__ staging, int nnzf, int nedge) {
    __shared__ int curs[NBUCK];
    const int t = threadIdx.x;
    for (int b = t; b < NBUCK; b += BINT) curs[b] = bbase[b] + pbb[blockIdx.x * NBUCK + b];
    __syncthreads();
    {
        const int per = (nnzf + BINB - 1) / BINB;
        const int beg = blockIdx.x * per;
        const int end = min(beg + per, nnzf);
        for (int i = beg + t; i < end; i += BINT) {
            const int   r = f_rows[i];
            const int   c = f_cols[i];
            const float v = f_vals[i];
            const int p = atomicAdd(&curs[r >> BSHIFT], 1);
            staging[p] = pack_cv(c, r & (BROWS - 1), v);
        }
    }
    {
        const int per = (nedge + BINB - 1) / BINB;
        const int beg = blockIdx.x * per;
        const int end = min(beg + per, nedge);
        for (int i = beg + t; i < end; i += BINT) {
            const int   r = a_rows[i] + N_NODES;
            const int   c = a_cols[i];
            const float v = a_vals[i];
            const int p = atomicAdd(&curs[r >> BSHIFT], 1);
            staging[p] = pack_cv(c, r & (BROWS - 1), v);
        }
    }
}

// Per-bucket sort: count rows in LDS -> scan -> row_ptr -> place into colval.
// Plain loads/stores: L2 assembles the bucket-contiguous write window into
// full lines (R15's nt-store variant broke this: 157MB writebacks, 1.5x slower).
__global__ __launch_bounds__(256) void sort_kernel(
        const int* __restrict__ cur, const int* __restrict__ bbase,
        const long long* __restrict__ staging, long long* __restrict__ colval,
        int* __restrict__ rp) {
    const int b = blockIdx.x;
    const int t = threadIdx.x;
    __shared__ int cnt[BROWS];
    __shared__ int offs[BROWS];
    cnt[t] = 0;
    __syncthreads();
    const int n = cur[b];
    const int base = bbase[b];
    const long long* seg = staging + base;
    for (int j = t; j < n; j += 256) {
        unsigned lo = (unsigned)(seg[j] & 0xffffffffLL);
        atomicAdd(&cnt[(lo >> 17) & (BROWS - 1)], 1);
    }
    __syncthreads();
    int v = cnt[t];
    offs[t] = v;
    __syncthreads();
    for (int o = 1; o < BROWS; o <<= 1) {
        int u = (t >= o) ? offs[t - o] : 0;
        __syncthreads();
        offs[t] += u;
        __syncthreads();
    }
    const int excl = offs[t] - v;
    offs[t] = base + excl;           // absolute placement cursor
    const int row = (b << BSHIFT) + t;
    if (row < VROWS) rp[row] = base + excl;
    __syncthreads();
    for (int j = t; j < n; j += 256) {
        long long e = seg[j];
        unsigned lo = (unsigned)(e & 0xffffffffLL);
        const int rl = (lo >> 17) & (BROWS - 1);
        const int p = atomicAdd(&offs[rl], 1);
        colval[p] = (long long)(lo & 0x1ffffu) | (e & 0xffffffff00000000LL);
    }
}

// ---------------- gathers: quarter-wave edges ----------------
// 16 lanes per edge, uint4 (16B = 8 bf16 ch) per lane -> 4 edges per gather
// instruction; ~0.5 vmem instr/edge. Each quarter owns one row.

// feat: gather from bf16 W, +bias, relu, bf16 out
__global__ __launch_bounds__(256) void spmm_feat_q_kernel(
        const int* __restrict__ rp, const long long* __restrict__ colval,
        const uint4* __restrict__ Wbf, const float* __restrict__ bias,
        unsigned short* __restrict__ base_bf, int n) {
    const int wave = (blockIdx.x * blockDim.x + threadIdx.x) >> 6;
    const int lane = threadIdx.x & 63;
    const int q = lane >> 4, ql = lane & 15;
    const int r = wave * 4 + q;
    float4 a0l = make_float4(0.f, 0.f, 0.f, 0.f), a0h = a0l, a1l = a0l, a1h = a0l;
    int i = 0, end = 0;
    if (r < n) { i = rp[r]; end = rp[r + 1]; }
    for (; i + 1 < end; i += 2) {
        int c0, c1; float v0, v1;
        nt_colval(colval + i,     c0, v0);
        nt_colval(colval + i + 1, c1, v1);
        const uint4 u0 = Wbf[c0 * 16 + ql];
        const uint4 u1 = Wbf[c1 * 16 + ql];
        fma8(a0l, a0h, v0, u0);
        fma8(a1l, a1h, v1, u1);
    }
    if (i < end) {
        int c; float v;
        nt_colval(colval + i, c, v);
        const uint4 u = Wbf[c * 16 + ql];
        fma8(a0l, a0h, v, u);
    }
    if (r < n) {
        const float4 bl = ((const float4*)bias)[ql * 2];
        const float4 bh = ((const float4*)bias)[ql * 2 + 1];
        float s0 = fmaxf(a0l.x + a1l.x + bl.x, 0.f), s1 = fmaxf(a0l.y + a1l.y + bl.y, 0.f);
        float s2 = fmaxf(a0l.z + a1l.z + bl.z, 0.f), s3 = fmaxf(a0l.w + a1l.w + bl.w, 0.f);
        float s4 = fmaxf(a0h.x + a1h.x + bh.x, 0.f), s5 = fmaxf(a0h.y + a1h.y + bh.y, 0.f);
        float s6 = fmaxf(a0h.z + a1h.z + bh.z, 0.f), s7 = fmaxf(a0h.w + a1h.w + bh.w, 0.f);
        uint4 o;
        o.x = (unsigned)f2bf(s0) | ((unsigned)f2bf(s1) << 16);
        o.y = (unsigned)f2bf(s2) | ((unsigned)f2bf(s3) << 16);
        o.z = (unsigned)f2bf(s4) | ((unsigned)f2bf(s5) << 16);
        o.w = (unsigned)f2bf(s6) | ((unsigned)f2bf(s7) << 16);
        ((uint4*)(base_bf + (size_t)r * 128))[ql] = o;
    }
}

// adj: bf16 src -> bf16 dst
__global__ __launch_bounds__(256) void spmm_adj_q_bf_kernel(
        const int* __restrict__ rp, const long long* __restrict__ colval,
        const uint4* __restrict__ src, unsigned short* __restrict__ dst, int n) {
    const int wave = (blockIdx.x * blockDim.x + threadIdx.x) >> 6;
    const int lane = threadIdx.x & 63;
    const int q = lane >> 4, ql = lane & 15;
    const int r = wave * 4 + q;
    float4 a0l = make_float4(0.f, 0.f, 0.f, 0.f), a0h = a0l, a1l = a0l, a1h = a0l;
    int i = 0, end = 0;
    if (r < n) { i = rp[r]; end = rp[r + 1]; }
    for (; i + 1 < end; i += 2) {
        int c0, c1; float v0, v1;
        nt_colval(colval + i,     c0, v0);
        nt_colval(colval + i + 1, c1, v1);
        const uint4 u0 = src[c0 * 16 + ql];
        const uint4 u1 = src[c1 * 16 + ql];
        fma8(a0l, a0h, v0, u0);
        fma8(a1l, a1h, v1, u1);
    }
    if (i < end) {
        int c; float v;
        nt_colval(colval + i, c, v);
        const uint4 u = src[c * 16 + ql];
        fma8(a0l, a0h, v, u);
    }
    if (r < n) {
        uint4 o;
        o.x = (unsigned)f2bf(a0l.x + a1l.x) | ((unsigned)f2bf(a0l.y + a1l.y) << 16);
        o.y = (unsigned)f2bf(a0l.z + a1l.z) | ((unsigned)f2bf(a0l.w + a1l.w) << 16);
        o.z = (unsigned)f2bf(a0h.x + a1h.x) | ((unsigned)f2bf(a0h.y + a1h.y) << 16);
        o.w = (unsigned)f2bf(a0h.z + a1h.z) | ((unsigned)f2bf(a0h.w + a1h.w) << 16);
        ((uint4*)(dst + (size_t)r * 128))[ql] = o;
    }
}

// adj: bf16 src -> f32 dst
__global__ __launch_bounds__(256) void spmm_adj_q_f32_kernel(
        const int* __restrict__ rp, const long long* __restrict__ colval,
        const uint4* __restrict__ src, float* __restrict__ dst, int n) {
    const int wave = (blockIdx.x * blockDim.x + threadIdx.x) >> 6;
    const int lane = threadIdx.x & 63;
    const int q = lane >> 4, ql = lane & 15;
    const int r = wave * 4 + q;
    float4 a0l = make_float4(0.f, 0.f, 0.f, 0.f), a0h = a0l, a1l = a0l, a1h = a0l;
    int i = 0, end = 0;
    if (r < n) { i = rp[r]; end = rp[r + 1]; }
    for (; i + 1 < end; i += 2) {
        int c0, c1; float v0, v1;
        nt_colval(colval + i,     c0, v0);
        nt_colval(colval + i + 1, c1, v1);
        const uint4 u0 = src[c0 * 16 + ql];
        const uint4 u1 = src[c1 * 16 + ql];
        fma8(a0l, a0h, v0, u0);
        fma8(a1l, a1h, v1, u1);
    }
    if (i < end) {
        int c; float v;
        nt_colval(colval + i, c, v);
        const uint4 u = src[c * 16 + ql];
        fma8(a0l, a0h, v, u);
    }
    if (r < n) {
        float4 lo, hi;
        lo.x = a0l.x + a1l.x; lo.y = a0l.y + a1l.y; lo.z = a0l.z + a1l.z; lo.w = a0l.w + a1l.w;
        hi.x = a0h.x + a1h.x; hi.y = a0h.y + a1h.y; hi.z = a0h.z + a1h.z; hi.w = a0h.w + a1h.w;
        float4* dr = (float4*)(dst + (size_t)r * 128);
        dr[ql * 2]     = lo;
        dr[ql * 2 + 1] = hi;
    }
}

// ---------------- launch ----------------

extern "C" void kernel_launch(void* const* d_in, const int* in_sizes, int n_in,
                              void* d_out, int out_size, void* d_ws, size_t ws_size,
                              hipStream_t stream) {
    const int*   fi   = (const int*)d_in[0];     // feat_indices [2, nnzf]
    const float* fv   = (const float*)d_in[1];   // feat_values  [nnzf]
    const int*   ai   = (const int*)d_in[2];     // adj_indices  [2, nedge]
    const float* av   = (const float*)d_in[3];   // adj_values   [nedge]
    const float* W    = (const float*)d_in[4];   // weight [512,128]
    const float* bias = (const float*)d_in[5];   // bias [1,128]
    float* out = (float*)d_out;

    const int nnzf  = in_sizes[1];
    const int nedge = in_sizes[3];
    const int ntot  = nnzf + nedge;
    const int* f_rows = fi;
    const int* f_cols = fi + nnzf;
    const int* a_rows = ai;
    const int* a_cols = ai + nedge;

    // bump-allocate workspace (256B aligned)
    char* wp = (char*)d_ws;
    auto balloc = [&](size_t bytes) -> char* {
        char* p = wp;
        wp += (bytes + 255) & ~(size_t)255;
        return p;
    };
    // staging (28.8MB) dead after sort; base_bf (25.6MB) overlays it.
    long long* staging = (long long*)balloc(8ull * (size_t)ntot);
    unsigned short* base_bf = (unsigned short*)staging;
    unsigned short* t1 = (unsigned short*)balloc(2ull * N_NODES * 128);
    long long* colval = (long long*)balloc(8ull * (size_t)ntot);
    int* rp     = (int*)balloc(4ull * (VROWS + 1));
    int* cur    = (int*)balloc(4ull * NBUCK);
    int* bbase  = (int*)balloc(4ull * NBUCK);
    int* pbb    = (int*)balloc(4ull * BINB * NBUCK);
    unsigned* Wbf = (unsigned*)balloc(4ull * 512 * 64);   // 128KB bf16 W

    const int nwaves = (N_NODES + 3) / 4;          // 4 rows per wave
    const int RW = (nwaves + 3) / 4;               // 4 waves per 256-thread block

    // ---- CSR build: memset -> histogram(+wconv) -> scan -> place -> sort ----
    hipMemsetAsync(cur, 0, 4ull * NBUCK, stream);
    binA_kernel<<<BINB, BINT, 0, stream>>>(f_rows, a_rows, cur, pbb, W, Wbf, nnzf, nedge);
    bucket_scan_kernel<<<1, 1024, 0, stream>>>(cur, bbase, rp);
    binB_kernel<<<BINB, BINT, 0, stream>>>(f_rows, f_cols, fv, a_rows, a_cols, av,
                                           bbase, pbb, staging, nnzf, nedge);
    sort_kernel<<<NBUCK, 256, 0, stream>>>(cur, bbase, staging, colval, rp);

    // ---- compute: feat -> base_bf(bf16), adj -> t1(bf16), adj -> out(f32) ----
    spmm_feat_q_kernel<<<RW, 256, 0, stream>>>(rp, colval, (const uint4*)Wbf, bias,
                                               base_bf, N_NODES);
    spmm_adj_q_bf_kernel<<<RW, 256, 0, stream>>>(rp + N_NODES, colval,
                                                 (const uint4*)base_bf, t1, N_NODES);
    spmm_adj_q_f32_kernel<<<RW, 256, 0, stream>>>(rp + N_NODES, colval,
                                                  (const uint4*)t1, out, N_NODES);
}